// Round 3
// baseline (2548.491 us; speedup 1.0000x reference)
//
#include <hip/hip_runtime.h>
#include <hip/hip_bf16.h>
#include <cstdint>

// Problem constants
#define BATCH 2048
#define MF    40                 // num fields
#define DDIM  64                 // embedding dim
#define LDIM  128                // hidden size per CIN layer
#define ROWS  (BATCH * DDIM)     // 131072 (b,d) rows

typedef __attribute__((ext_vector_type(4)))  short   short4_t;
typedef __attribute__((ext_vector_type(8)))  short   short8;
typedef __attribute__((ext_vector_type(8)))  __bf16  bf16x8;
typedef __attribute__((ext_vector_type(4)))  float   floatx4;
typedef __attribute__((ext_vector_type(16))) float   floatx16;

__device__ __forceinline__ unsigned short f32_to_bf16(float f) {
    union { float f; uint32_t u; } v; v.f = f;
    uint32_t u = v.u;
    uint32_t r = (u + 0x7fffu + ((u >> 16) & 1u)) >> 16;   // RNE
    return (unsigned short)r;
}

// ---------------------------------------------------------------------------
// W prep: swizzle W into exact B-fragment order (bf16 RNE, zero-padded h>=H):
//   Wt[m][kk][cb][lane][j] = W[m][ kk*16 + (lane>>5)*8 + j ][ cb*32 + (lane&31) ]
// One wave per (m,kk,cb).
// ---------------------------------------------------------------------------
__global__ void k_wprep(const float* __restrict__ W, unsigned short* __restrict__ Wt,
                        int KK, int H) {
    int bi = blockIdx.x;                 // (m*KK + kk)*4 + cb
    int lane = threadIdx.x;
    int cb = bi & 3;
    int mkk = bi >> 2;
    int kk = mkk % KK, m = mkk / KK;
    int l = cb * 32 + (lane & 31);
    int hbase = kk * 16 + (lane >> 5) * 8;
    unsigned short o[8];
#pragma unroll
    for (int j = 0; j < 8; ++j) {
        int h = hbase + j;
        float v = (h < H) ? W[((size_t)m * H + h) * LDIM + l] : 0.f;
        o[j] = f32_to_bf16(v);
    }
    *(short8*)(Wt + ((size_t)bi * 64 + lane) * 8) = *(const short8*)o;
}

// ---------------------------------------------------------------------------
// Core GEMM + scale + fused column-sum.
//   out_acc[row,l] = sum_m x[b,m,d] * (XK[row,:] @ W[m,:,:])[l],  row=(b,d)
// Block = 512 thr = 8 waves: wave w handles batch (blockIdx*4 + (w>>1)),
// columns (w&1)*64 .. +63. One shared W[m] double-buffer (KK*4KB x2) serves
// all 8 waves -> 2 blocks/CU = 16 waves/CU = 4 waves/SIMD (needs VGPR<=128).
//   - A-frags (XK) loaded once per wave, reused over all 40 m
//   - W[m] slab double-buffered in LDS via global_load_lds x16B, prefetch m+1
//   - per-m fp32 epilogue: acc += s_m(row) * P_m
//   - Xout written in C-fragment layout (coalesced b64 stores)
//   - ps (sum over d) computed in-register + shfl_xor(32)
// ---------------------------------------------------------------------------
template <int KK, bool FIRST, int OFF, bool WRITEX>
__global__ __launch_bounds__(512, 4) void k_gemm(
    const float* __restrict__ x,               // fp32 [B][MF][DDIM]
    const unsigned short* __restrict__ Xprev,  // bf16 frag-layout (unused if FIRST)
    const unsigned short* __restrict__ Wt,     // bf16 [MF][KK*2048]
    unsigned short* __restrict__ Xout,         // bf16 frag-layout (unused if !WRITEX)
    float* __restrict__ out)                   // fp32 [B][384]
{
    __shared__ unsigned short slab[2][KK * 2048];

    const int tid  = threadIdx.x;
    const int lane = tid & 63, wave = tid >> 6;
    const int hf   = lane >> 5, r31 = lane & 31;
    const int rowidx = wave >> 1, colhalf = wave & 1;
    const int b = blockIdx.x * 4 + rowidx;     // this wave's batch

    // ---- A fragments, once: afrag[t][kk], A[row=r31][k=hf*8+j] ----
    bf16x8 afrag[2][KK];
    if constexpr (FIRST) {
#pragma unroll
        for (int t = 0; t < 2; ++t)
#pragma unroll
            for (int kk = 0; kk < KK; ++kk) {
                unsigned short tmp[8];
#pragma unroll
                for (int j = 0; j < 8; ++j) {
                    int h = kk * 16 + hf * 8 + j;
                    float v = (h < MF) ? x[((size_t)b * MF + h) * DDIM + t * 32 + r31] : 0.f;
                    tmp[j] = f32_to_bf16(v);
                }
                afrag[t][kk] = __builtin_bit_cast(bf16x8, *(const short8*)tmp);
            }
    } else {
        const int g = r31 >> 3, hs = (r31 >> 2) & 1, ii = r31 & 3;
#pragma unroll
        for (int t = 0; t < 2; ++t) {
            int tile = b * 2 + t;
#pragma unroll
            for (int kk = 0; kk < KK; ++kk) {
                int k0  = kk * 16 + hf * 8;
                int cbk = k0 >> 5, rr = k0 & 31;
                const unsigned short* p =
                    Xprev + ((size_t)(((tile * 4 + cbk) * 4 + g) * 2 + hs) * 32 + rr) * 4 + ii;
                unsigned short tmp[8];
#pragma unroll
                for (int j = 0; j < 8; ++j) tmp[j] = p[(size_t)j * 4];
                afrag[t][kk] = __builtin_bit_cast(bf16x8, *(const short8*)tmp);
            }
        }
    }

    floatx16 acc[2][2] = {};   // [tile][cb']

    auto stage = [&](int m, int buf) {
        const unsigned short* src = Wt + (size_t)m * (KK * 2048);
        constexpr int CHUNKS = KK * 256;                   // 16B chunks in slab
#pragma unroll
        for (int it = 0; it < (CHUNKS + 511) / 512; ++it) {
            int c = it * 512 + tid;
            if (CHUNKS % 512 == 0 || c < CHUNKS)           // wave-granular guard
                __builtin_amdgcn_global_load_lds(
                    (const __attribute__((address_space(1))) uint32_t*)(src + (size_t)c * 8),
                    (__attribute__((address_space(3))) uint32_t*)(&slab[buf][(size_t)c * 8]),
                    16, 0, 0);
        }
    };

    stage(0, 0);
#pragma unroll 1
    for (int m = 0; m < MF; ++m) {
        asm volatile("s_waitcnt vmcnt(0)" ::: "memory");   // slab[m&1] staged
        __syncthreads();
        if (m + 1 < MF) stage(m + 1, (m + 1) & 1);         // prefetch overlaps compute

        const unsigned short* sl = slab[m & 1];
        const floatx4* sp4 = (const floatx4*)(x + ((size_t)b * MF + m) * DDIM);

#pragma unroll
        for (int cbp = 0; cbp < 2; ++cbp) {
            const int cbg = colhalf * 2 + cbp;
            floatx16 P0{}, P1{};
#pragma unroll
            for (int kk = 0; kk < KK; ++kk) {
                bf16x8 bf = __builtin_bit_cast(
                    bf16x8, *(const short8*)(sl + ((size_t)(kk * 4 + cbg) * 64 + lane) * 8));
                P0 = __builtin_amdgcn_mfma_f32_32x32x16_bf16(afrag[0][kk], bf, P0, 0, 0, 0);
                P1 = __builtin_amdgcn_mfma_f32_32x32x16_bf16(afrag[1][kk], bf, P1, 0, 0, 0);
            }
            // fp32 epilogue: acc += s (per row) * P
            // C/D: col = r31, row = (j&3) + 8*(j>>2) + 4*hf (+32*tile)
#pragma unroll
            for (int g = 0; g < 4; ++g) {
                floatx4 s0 = sp4[hf + 2 * g];          // tile0: d = 4hf+8g+i
                floatx4 s1 = sp4[8 + hf + 2 * g];      // tile1: d = 32+...
#pragma unroll
                for (int i = 0; i < 4; ++i) {
                    acc[0][cbp][g * 4 + i] += s0[i] * P0[g * 4 + i];
                    acc[1][cbp][g * 4 + i] += s1[i] * P1[g * 4 + i];
                }
            }
        }
    }

    // ---- store x_next in C-fragment layout (coalesced b64 stores) ----
    if constexpr (WRITEX) {
#pragma unroll
        for (int t = 0; t < 2; ++t) {
            int tile = b * 2 + t;
#pragma unroll
            for (int cbp = 0; cbp < 2; ++cbp) {
                int cb = colhalf * 2 + cbp;
#pragma unroll
                for (int g = 0; g < 4; ++g) {
                    unsigned short o[4];
#pragma unroll
                    for (int i = 0; i < 4; ++i) o[i] = f32_to_bf16(acc[t][cbp][g * 4 + i]);
                    *(short4_t*)(Xout +
                        ((size_t)(((tile * 4 + cb) * 4 + g) * 2 + hf) * 32 + r31) * 4) =
                        *(const short4_t*)o;
                }
            }
        }
    }

    // ---- fused ps: out[b][OFF + l] = sum_d acc (fp32, all 64 d in-wave) ----
#pragma unroll
    for (int cbp = 0; cbp < 2; ++cbp) {
        float v = 0.f;
#pragma unroll
        for (int j = 0; j < 16; ++j) v += acc[0][cbp][j] + acc[1][cbp][j];
        v += __shfl_xor(v, 32);                         // other hf: remaining rows
        if (hf == 0)
            out[(size_t)b * 384 + OFF + (colhalf * 2 + cbp) * 32 + r31] = v;
    }
}

// ---------------------------------------------------------------------------
extern "C" void kernel_launch(void* const* d_in, const int* in_sizes, int n_in,
                              void* d_out, int out_size, void* d_ws, size_t ws_size,
                              hipStream_t stream) {
    const float* x  = (const float*)d_in[0];
    const float* W0 = (const float*)d_in[1];
    const float* W1 = (const float*)d_in[2];
    const float* W2 = (const float*)d_in[3];
    float* out = (float*)d_out;

    char* ws = (char*)d_ws;
    size_t off = 0;
    auto alloc = [&](size_t bytes) -> void* {
        void* p = ws + off;
        off += (bytes + 255) & ~(size_t)255;
        return p;
    };
    unsigned short* W0t = (unsigned short*)alloc((size_t)MF * 3 * 2048 * 2);   // 0.5 MB
    unsigned short* W1t = (unsigned short*)alloc((size_t)MF * 8 * 2048 * 2);   // 1.3 MB
    unsigned short* W2t = (unsigned short*)alloc((size_t)MF * 8 * 2048 * 2);   // 1.3 MB
    unsigned short* X1p = (unsigned short*)alloc((size_t)ROWS * LDIM * 2);     // 33.5 MB
    unsigned short* X2p = (unsigned short*)alloc((size_t)ROWS * LDIM * 2);     // 33.5 MB

    k_wprep<<<MF * 3 * 4, 64, 0, stream>>>(W0, W0t, 3, 40);
    k_wprep<<<MF * 8 * 4, 64, 0, stream>>>(W1, W1t, 8, 128);
    k_wprep<<<MF * 8 * 4, 64, 0, stream>>>(W2, W2t, 8, 128);

    k_gemm<3, true,  0,   true ><<<ROWS / 256, 512, 0, stream>>>(x, nullptr, W0t, X1p, out);
    k_gemm<8, false, 128, true ><<<ROWS / 256, 512, 0, stream>>>(x, X1p,     W1t, X2p, out);
    k_gemm<8, false, 256, false><<<ROWS / 256, 512, 0, stream>>>(x, X2p,     W2t, X2p, out);
}

// Round 4
// 466.791 us; speedup vs baseline: 5.4596x; 5.4596x over previous
//
#include <hip/hip_runtime.h>
#include <hip/hip_bf16.h>
#include <cstdint>

// Problem constants
#define BATCH 2048
#define MF    40                 // num fields
#define DDIM  64                 // embedding dim
#define LDIM  128                // hidden size per CIN layer
#define ROWS  (BATCH * DDIM)     // 131072 (b,d) rows

typedef __attribute__((ext_vector_type(4)))  short   short4_t;
typedef __attribute__((ext_vector_type(8)))  short   short8;
typedef __attribute__((ext_vector_type(8)))  __bf16  bf16x8;
typedef __attribute__((ext_vector_type(4)))  float   floatx4;
typedef __attribute__((ext_vector_type(16))) float   floatx16;

__device__ __forceinline__ unsigned short f32_to_bf16(float f) {
    union { float f; uint32_t u; } v; v.f = f;
    uint32_t u = v.u;
    uint32_t r = (u + 0x7fffu + ((u >> 16) & 1u)) >> 16;   // RNE
    return (unsigned short)r;
}

// ---------------------------------------------------------------------------
// W prep: swizzle W into exact B-fragment order (bf16 RNE, zero-padded h>=H):
//   Wt[m][kk][cb][lane][j] = W[m][ kk*16 + (lane>>5)*8 + j ][ cb*32 + (lane&31) ]
// One wave per (m,kk,cb).
// ---------------------------------------------------------------------------
__global__ void k_wprep(const float* __restrict__ W, unsigned short* __restrict__ Wt,
                        int KK, int H) {
    int bi = blockIdx.x;                 // (m*KK + kk)*4 + cb
    int lane = threadIdx.x;
    int cb = bi & 3;
    int mkk = bi >> 2;
    int kk = mkk % KK, m = mkk / KK;
    int l = cb * 32 + (lane & 31);
    int hbase = kk * 16 + (lane >> 5) * 8;
    unsigned short o[8];
#pragma unroll
    for (int j = 0; j < 8; ++j) {
        int h = hbase + j;
        float v = (h < H) ? W[((size_t)m * H + h) * LDIM + l] : 0.f;
        o[j] = f32_to_bf16(v);
    }
    *(short8*)(Wt + ((size_t)bi * 64 + lane) * 8) = *(const short8*)o;
}

// ---------------------------------------------------------------------------
// Core GEMM + scale + fused column-sum.
//   out_acc[row,l] = sum_m x[b,m,d] * (XK[row,:] @ W[m,:,:])[l],  row=(b,d)
// Block = 256 thr = 4 waves in a 2x2 (rowhalf x colhalf) grid over a
// 128-row x 128-col tile. Each wave: 64 rows (one batch b) x 64 cols.
//   - A-frags (XK) loaded once per wave, reused over all 40 m
//   - W[m] slab (KK*4KB) double-buffered in LDS via global_load_lds x16B
//   - kk-outer inner loop: 4 independent MFMA chains P[tile][cbp], b-frag
//     for kk+1 prefetched under kk's MFMAs
//   - scale vectors for m hoisted before the MFMA region
//   - per-m fp32 epilogue: acc += s_m(row) * P_m
//   - Xout written in C-fragment layout (coalesced b64 stores)
//   - ps (sum over d) computed in-register + shfl_xor(32)
// NOTE: __launch_bounds__(256,2) -> 256-reg/wave budget. (512,4) in round 3
// capped VGPRs at 64 and spilled catastrophically — do not revisit.
// ---------------------------------------------------------------------------
template <int KK, bool FIRST, int OFF, bool WRITEX>
__global__ __launch_bounds__(256, 2) void k_gemm(
    const float* __restrict__ x,               // fp32 [B][MF][DDIM]
    const unsigned short* __restrict__ Xprev,  // bf16 frag-layout (unused if FIRST)
    const unsigned short* __restrict__ Wt,     // bf16 [MF][KK*2048]
    unsigned short* __restrict__ Xout,         // bf16 frag-layout (unused if !WRITEX)
    float* __restrict__ out)                   // fp32 [B][384]
{
    __shared__ unsigned short slab[2][KK * 2048];

    const int tid  = threadIdx.x;
    const int lane = tid & 63, wave = tid >> 6;
    const int hf   = lane >> 5, r31 = lane & 31;
    const int rowhalf = wave >> 1, colhalf = wave & 1;
    const int b = blockIdx.x * 2 + rowhalf;    // this wave's batch

    // ---- A fragments, once: afrag[t][kk], A[row=r31][k=hf*8+j] ----
    bf16x8 afrag[2][KK];
    if constexpr (FIRST) {
#pragma unroll
        for (int t = 0; t < 2; ++t)
#pragma unroll
            for (int kk = 0; kk < KK; ++kk) {
                unsigned short tmp[8];
#pragma unroll
                for (int j = 0; j < 8; ++j) {
                    int h = kk * 16 + hf * 8 + j;
                    float v = (h < MF) ? x[((size_t)b * MF + h) * DDIM + t * 32 + r31] : 0.f;
                    tmp[j] = f32_to_bf16(v);
                }
                afrag[t][kk] = __builtin_bit_cast(bf16x8, *(const short8*)tmp);
            }
    } else {
        const int g = r31 >> 3, hs = (r31 >> 2) & 1, ii = r31 & 3;
#pragma unroll
        for (int t = 0; t < 2; ++t) {
            int tile = b * 2 + t;
#pragma unroll
            for (int kk = 0; kk < KK; ++kk) {
                int k0  = kk * 16 + hf * 8;
                int cbk = k0 >> 5, rr = k0 & 31;
                const unsigned short* p =
                    Xprev + ((size_t)(((tile * 4 + cbk) * 4 + g) * 2 + hs) * 32 + rr) * 4 + ii;
                unsigned short tmp[8];
#pragma unroll
                for (int j = 0; j < 8; ++j) tmp[j] = p[(size_t)j * 4];
                afrag[t][kk] = __builtin_bit_cast(bf16x8, *(const short8*)tmp);
            }
        }
    }

    floatx16 acc[2][2] = {};   // [tile][cbp]

    auto stage = [&](int m, int buf) {
        const unsigned short* src = Wt + (size_t)m * (KK * 2048);
#pragma unroll
        for (int it = 0; it < KK; ++it) {
            int c = it * 256 + tid;                    // 16B chunk index
            __builtin_amdgcn_global_load_lds(
                (const __attribute__((address_space(1))) uint32_t*)(src + (size_t)c * 8),
                (__attribute__((address_space(3))) uint32_t*)(&slab[buf][(size_t)c * 8]),
                16, 0, 0);
        }
    };

    const int cbg0 = colhalf * 2, cbg1 = colhalf * 2 + 1;

    stage(0, 0);
#pragma unroll 1
    for (int m = 0; m < MF; ++m) {
        asm volatile("s_waitcnt vmcnt(0)" ::: "memory");   // slab[m&1] staged
        __syncthreads();
        if (m + 1 < MF) stage(m + 1, (m + 1) & 1);         // prefetch overlaps compute

        const unsigned short* sl = slab[m & 1];

        // hoist scale vectors: latency hides under the MFMA region below
        const floatx4* sp4 = (const floatx4*)(x + ((size_t)b * MF + m) * DDIM);
        floatx4 sc[2][4];
#pragma unroll
        for (int g = 0; g < 4; ++g) {
            sc[0][g] = sp4[hf + 2 * g];        // tile0 rows: d = 4hf + 8g + i
            sc[1][g] = sp4[8 + hf + 2 * g];    // tile1 rows: d = 32 + ...
        }

        // kk-outer, 4 independent MFMA chains; prefetch kk+1's b-frags
        floatx16 P[2][2] = {};
        bf16x8 bcur0 = __builtin_bit_cast(
            bf16x8, *(const short8*)(sl + ((size_t)(0 * 4 + cbg0) * 64 + lane) * 8));
        bf16x8 bcur1 = __builtin_bit_cast(
            bf16x8, *(const short8*)(sl + ((size_t)(0 * 4 + cbg1) * 64 + lane) * 8));
#pragma unroll
        for (int kk = 0; kk < KK; ++kk) {
            bf16x8 bnxt0, bnxt1;
            if (kk + 1 < KK) {
                bnxt0 = __builtin_bit_cast(
                    bf16x8, *(const short8*)(sl + ((size_t)((kk + 1) * 4 + cbg0) * 64 + lane) * 8));
                bnxt1 = __builtin_bit_cast(
                    bf16x8, *(const short8*)(sl + ((size_t)((kk + 1) * 4 + cbg1) * 64 + lane) * 8));
            }
            P[0][0] = __builtin_amdgcn_mfma_f32_32x32x16_bf16(afrag[0][kk], bcur0, P[0][0], 0, 0, 0);
            P[1][0] = __builtin_amdgcn_mfma_f32_32x32x16_bf16(afrag[1][kk], bcur0, P[1][0], 0, 0, 0);
            P[0][1] = __builtin_amdgcn_mfma_f32_32x32x16_bf16(afrag[0][kk], bcur1, P[0][1], 0, 0, 0);
            P[1][1] = __builtin_amdgcn_mfma_f32_32x32x16_bf16(afrag[1][kk], bcur1, P[1][1], 0, 0, 0);
            if (kk + 1 < KK) { bcur0 = bnxt0; bcur1 = bnxt1; }
        }

        // fp32 epilogue: acc += s (per row) * P
        // C/D: col = r31, row = (j&3) + 8*(j>>2) + 4*hf (+32*tile)
#pragma unroll
        for (int t = 0; t < 2; ++t)
#pragma unroll
            for (int cbp = 0; cbp < 2; ++cbp)
#pragma unroll
                for (int g = 0; g < 4; ++g)
#pragma unroll
                    for (int i = 0; i < 4; ++i)
                        acc[t][cbp][g * 4 + i] += sc[t][g][i] * P[t][cbp][g * 4 + i];
    }

    // ---- store x_next in C-fragment layout (coalesced b64 stores) ----
    if constexpr (WRITEX) {
#pragma unroll
        for (int t = 0; t < 2; ++t) {
            int tile = b * 2 + t;
#pragma unroll
            for (int cbp = 0; cbp < 2; ++cbp) {
                int cb = colhalf * 2 + cbp;
#pragma unroll
                for (int g = 0; g < 4; ++g) {
                    unsigned short o[4];
#pragma unroll
                    for (int i = 0; i < 4; ++i) o[i] = f32_to_bf16(acc[t][cbp][g * 4 + i]);
                    *(short4_t*)(Xout +
                        ((size_t)(((tile * 4 + cb) * 4 + g) * 2 + hf) * 32 + r31) * 4) =
                        *(const short4_t*)o;
                }
            }
        }
    }

    // ---- fused ps: out[b][OFF + l] = sum_d acc (fp32, all 64 d in-wave) ----
#pragma unroll
    for (int cbp = 0; cbp < 2; ++cbp) {
        float v = 0.f;
#pragma unroll
        for (int j = 0; j < 16; ++j) v += acc[0][cbp][j] + acc[1][cbp][j];
        v += __shfl_xor(v, 32);                         // other hf: remaining rows
        if (hf == 0)
            out[(size_t)b * 384 + OFF + (colhalf * 2 + cbp) * 32 + r31] = v;
    }
}

// ---------------------------------------------------------------------------
extern "C" void kernel_launch(void* const* d_in, const int* in_sizes, int n_in,
                              void* d_out, int out_size, void* d_ws, size_t ws_size,
                              hipStream_t stream) {
    const float* x  = (const float*)d_in[0];
    const float* W0 = (const float*)d_in[1];
    const float* W1 = (const float*)d_in[2];
    const float* W2 = (const float*)d_in[3];
    float* out = (float*)d_out;

    char* ws = (char*)d_ws;
    size_t off = 0;
    auto alloc = [&](size_t bytes) -> void* {
        void* p = ws + off;
        off += (bytes + 255) & ~(size_t)255;
        return p;
    };
    unsigned short* W0t = (unsigned short*)alloc((size_t)MF * 3 * 2048 * 2);   // 0.5 MB
    unsigned short* W1t = (unsigned short*)alloc((size_t)MF * 8 * 2048 * 2);   // 1.3 MB
    unsigned short* W2t = (unsigned short*)alloc((size_t)MF * 8 * 2048 * 2);   // 1.3 MB
    unsigned short* X1p = (unsigned short*)alloc((size_t)ROWS * LDIM * 2);     // 33.5 MB
    unsigned short* X2p = (unsigned short*)alloc((size_t)ROWS * LDIM * 2);     // 33.5 MB

    k_wprep<<<MF * 3 * 4, 64, 0, stream>>>(W0, W0t, 3, 40);
    k_wprep<<<MF * 8 * 4, 64, 0, stream>>>(W1, W1t, 8, 128);
    k_wprep<<<MF * 8 * 4, 64, 0, stream>>>(W2, W2t, 8, 128);

    k_gemm<3, true,  0,   true ><<<ROWS / 128, 256, 0, stream>>>(x, nullptr, W0t, X1p, out);
    k_gemm<8, false, 128, true ><<<ROWS / 128, 256, 0, stream>>>(x, X1p,     W1t, X2p, out);
    k_gemm<8, false, 256, false><<<ROWS / 128, 256, 0, stream>>>(x, X2p,     W2t, X2p, out);
}

// Round 5
// 465.771 us; speedup vs baseline: 5.4716x; 1.0022x over previous
//
#include <hip/hip_runtime.h>
#include <hip/hip_bf16.h>
#include <cstdint>

// Problem constants
#define BATCH 2048
#define MF    40                 // num fields
#define DDIM  64                 // embedding dim
#define LDIM  128                // hidden size per CIN layer
#define ROWS  (BATCH * DDIM)     // 131072 (b,d) rows

typedef __attribute__((ext_vector_type(4)))  short   short4_t;
typedef __attribute__((ext_vector_type(8)))  short   short8;
typedef __attribute__((ext_vector_type(8)))  __bf16  bf16x8;
typedef __attribute__((ext_vector_type(4)))  float   floatx4;
typedef __attribute__((ext_vector_type(16))) float   floatx16;

__device__ __forceinline__ unsigned short f32_to_bf16(float f) {
    union { float f; uint32_t u; } v; v.f = f;
    uint32_t u = v.u;
    uint32_t r = (u + 0x7fffu + ((u >> 16) & 1u)) >> 16;   // RNE
    return (unsigned short)r;
}

// ---------------------------------------------------------------------------
// W prep: swizzle W into exact B-fragment order (bf16 RNE, zero-padded h>=H):
//   Wt[m][kk][cb][lane][j] = W[m][ kk*16 + (lane>>5)*8 + j ][ cb*32 + (lane&31) ]
// One wave per (m,kk,cb).
// ---------------------------------------------------------------------------
__global__ void k_wprep(const float* __restrict__ W, unsigned short* __restrict__ Wt,
                        int KK, int H) {
    int bi = blockIdx.x;                 // (m*KK + kk)*4 + cb
    int lane = threadIdx.x;
    int cb = bi & 3;
    int mkk = bi >> 2;
    int kk = mkk % KK, m = mkk / KK;
    int l = cb * 32 + (lane & 31);
    int hbase = kk * 16 + (lane >> 5) * 8;
    unsigned short o[8];
#pragma unroll
    for (int j = 0; j < 8; ++j) {
        int h = hbase + j;
        float v = (h < H) ? W[((size_t)m * H + h) * LDIM + l] : 0.f;
        o[j] = f32_to_bf16(v);
    }
    *(short8*)(Wt + ((size_t)bi * 64 + lane) * 8) = *(const short8*)o;
}

// ---------------------------------------------------------------------------
// Core GEMM + scale + fused column-sum.
//   out_acc[row,l] = sum_m x[b,m,d] * (XK[row,:] @ W[m,:,:])[l],  row=(b,d)
// Block = 256 thr = 4 waves (2x2 over a 128-row x 128-col tile); each wave:
// one batch b (64 rows) x 64 cols.
//   - A-frags loaded once per wave, reused over all 40 m
//   - W[m] slab (KK*4KB) double-buffered in LDS via global_load_lds x16B
//   - 3-deep REGISTER pipeline of b-frags from LDS (covers ~140cy ds latency;
//     round 4's 1-deep pipeline stalled the matrix pipe every kk-step)
//   - sc loads issued BEFORE stage(m+1): epilogue sc-wait leaves staging
//     loads in flight (no per-m vmcnt(0) drain from the epilogue)
//   - per-m fp32 epilogue: acc += s_m(row) * P_m
//   - Xout in C-fragment layout; ps fused via in-reg sum + shfl_xor(32)
// NOTE: (256,2) -> 256 unified regs/wave. (512,4) in round 3 capped at 64
// arch VGPRs and spilled catastrophically — do not revisit.
// ---------------------------------------------------------------------------
template <int KK, bool FIRST, int OFF, bool WRITEX>
__global__ __launch_bounds__(256, 2) void k_gemm(
    const float* __restrict__ x,               // fp32 [B][MF][DDIM]
    const unsigned short* __restrict__ Xprev,  // bf16 frag-layout (unused if FIRST)
    const unsigned short* __restrict__ Wt,     // bf16 [MF][KK*2048]
    unsigned short* __restrict__ Xout,         // bf16 frag-layout (unused if !WRITEX)
    float* __restrict__ out)                   // fp32 [B][384]
{
    __shared__ unsigned short slab[2][KK * 2048];

    const int tid  = threadIdx.x;
    const int lane = tid & 63, wave = tid >> 6;
    const int hf   = lane >> 5, r31 = lane & 31;
    const int rowhalf = wave >> 1, colhalf = wave & 1;
    const int b = blockIdx.x * 2 + rowhalf;    // this wave's batch

    // ---- A fragments, once: afrag[t][kk], A[row=r31][k=hf*8+j] ----
    bf16x8 afrag[2][KK];
    if constexpr (FIRST) {
#pragma unroll
        for (int t = 0; t < 2; ++t)
#pragma unroll
            for (int kk = 0; kk < KK; ++kk) {
                unsigned short tmp[8];
#pragma unroll
                for (int j = 0; j < 8; ++j) {
                    int h = kk * 16 + hf * 8 + j;
                    float v = (h < MF) ? x[((size_t)b * MF + h) * DDIM + t * 32 + r31] : 0.f;
                    tmp[j] = f32_to_bf16(v);
                }
                afrag[t][kk] = __builtin_bit_cast(bf16x8, *(const short8*)tmp);
            }
    } else {
        const int g = r31 >> 3, hs = (r31 >> 2) & 1, ii = r31 & 3;
#pragma unroll
        for (int t = 0; t < 2; ++t) {
            int tile = b * 2 + t;
#pragma unroll
            for (int kk = 0; kk < KK; ++kk) {
                int k0  = kk * 16 + hf * 8;
                int cbk = k0 >> 5, rr = k0 & 31;
                const unsigned short* p =
                    Xprev + ((size_t)(((tile * 4 + cbk) * 4 + g) * 2 + hs) * 32 + rr) * 4 + ii;
                unsigned short tmp[8];
#pragma unroll
                for (int j = 0; j < 8; ++j) tmp[j] = p[(size_t)j * 4];
                afrag[t][kk] = __builtin_bit_cast(bf16x8, *(const short8*)tmp);
            }
        }
    }

    floatx16 acc[2][2] = {};   // [tile][cbp]

    auto stage = [&](int m, int buf) {
        const unsigned short* src = Wt + (size_t)m * (KK * 2048);
#pragma unroll
        for (int it = 0; it < KK; ++it) {
            int c = it * 256 + tid;                    // 16B chunk index
            __builtin_amdgcn_global_load_lds(
                (const __attribute__((address_space(1))) uint32_t*)(src + (size_t)c * 8),
                (__attribute__((address_space(3))) uint32_t*)(&slab[buf][(size_t)c * 8]),
                16, 0, 0);
        }
    };

    const int cbg0 = colhalf * 2, cbg1 = colhalf * 2 + 1;
    auto ldfrag = [&](const unsigned short* sl, int kk, int cb) {
        return __builtin_bit_cast(
            bf16x8, *(const short8*)(sl + ((size_t)(kk * 4 + cb) * 64 + lane) * 8));
    };

    constexpr int D = (KK < 3) ? KK : 3;   // b-frag register-pipeline depth

    stage(0, 0);
#pragma unroll 1
    for (int m = 0; m < MF; ++m) {
        asm volatile("s_waitcnt vmcnt(0)" ::: "memory");   // slab[m&1] staged
        __syncthreads();

        // sc loads FIRST, then stage(m+1): epilogue's sc-wait then leaves the
        // staging loads outstanding (vmcnt(16), not a drain)
        const floatx4* sp4 = (const floatx4*)(x + ((size_t)b * MF + m) * DDIM);
        floatx4 sc0[4], sc1[4];
#pragma unroll
        for (int g = 0; g < 4; ++g) {
            sc0[g] = sp4[hf + 2 * g];          // tile0 rows: d = 4hf + 8g + i
            sc1[g] = sp4[8 + hf + 2 * g];      // tile1 rows: d = 32 + ...
        }
        if (m + 1 < MF) stage(m + 1, (m + 1) & 1);         // prefetch overlaps compute

        const unsigned short* sl = slab[m & 1];

        // prime D pipeline slots
        bf16x8 bbuf[D][2];
#pragma unroll
        for (int p = 0; p < D; ++p) {
            bbuf[p][0] = ldfrag(sl, p, cbg0);
            bbuf[p][1] = ldfrag(sl, p, cbg1);
        }

        floatx16 P[2][2] = {};
#pragma unroll
        for (int kk = 0; kk < KK; ++kk) {
            const int slot = kk % D;
            P[0][0] = __builtin_amdgcn_mfma_f32_32x32x16_bf16(afrag[0][kk], bbuf[slot][0], P[0][0], 0, 0, 0);
            P[1][0] = __builtin_amdgcn_mfma_f32_32x32x16_bf16(afrag[1][kk], bbuf[slot][0], P[1][0], 0, 0, 0);
            P[0][1] = __builtin_amdgcn_mfma_f32_32x32x16_bf16(afrag[0][kk], bbuf[slot][1], P[0][1], 0, 0, 0);
            P[1][1] = __builtin_amdgcn_mfma_f32_32x32x16_bf16(afrag[1][kk], bbuf[slot][1], P[1][1], 0, 0, 0);
            if (kk + D < KK) {
                bbuf[slot][0] = ldfrag(sl, kk + D, cbg0);
                bbuf[slot][1] = ldfrag(sl, kk + D, cbg1);
            }
        }

        // fp32 epilogue: acc += s (per row) * P
        // C/D: col = r31, row = (j&3) + 8*(j>>2) + 4*hf (+32*tile)
#pragma unroll
        for (int cbp = 0; cbp < 2; ++cbp)
#pragma unroll
            for (int g = 0; g < 4; ++g)
#pragma unroll
                for (int i = 0; i < 4; ++i) {
                    acc[0][cbp][g * 4 + i] += sc0[g][i] * P[0][cbp][g * 4 + i];
                    acc[1][cbp][g * 4 + i] += sc1[g][i] * P[1][cbp][g * 4 + i];
                }
    }

    // ---- store x_next in C-fragment layout (coalesced b64 stores) ----
    if constexpr (WRITEX) {
#pragma unroll
        for (int t = 0; t < 2; ++t) {
            int tile = b * 2 + t;
#pragma unroll
            for (int cbp = 0; cbp < 2; ++cbp) {
                int cb = colhalf * 2 + cbp;
#pragma unroll
                for (int g = 0; g < 4; ++g) {
                    unsigned short o[4];
#pragma unroll
                    for (int i = 0; i < 4; ++i) o[i] = f32_to_bf16(acc[t][cbp][g * 4 + i]);
                    *(short4_t*)(Xout +
                        ((size_t)(((tile * 4 + cb) * 4 + g) * 2 + hf) * 32 + r31) * 4) =
                        *(const short4_t*)o;
                }
            }
        }
    }

    // ---- fused ps: out[b][OFF + l] = sum_d acc (fp32, all 64 d in-wave) ----
#pragma unroll
    for (int cbp = 0; cbp < 2; ++cbp) {
        float v = 0.f;
#pragma unroll
        for (int j = 0; j < 16; ++j) v += acc[0][cbp][j] + acc[1][cbp][j];
        v += __shfl_xor(v, 32);                         // other hf: remaining rows
        if (hf == 0)
            out[(size_t)b * 384 + OFF + (colhalf * 2 + cbp) * 32 + r31] = v;
    }
}

// ---------------------------------------------------------------------------
extern "C" void kernel_launch(void* const* d_in, const int* in_sizes, int n_in,
                              void* d_out, int out_size, void* d_ws, size_t ws_size,
                              hipStream_t stream) {
    const float* x  = (const float*)d_in[0];
    const float* W0 = (const float*)d_in[1];
    const float* W1 = (const float*)d_in[2];
    const float* W2 = (const float*)d_in[3];
    float* out = (float*)d_out;

    char* ws = (char*)d_ws;
    size_t off = 0;
    auto alloc = [&](size_t bytes) -> void* {
        void* p = ws + off;
        off += (bytes + 255) & ~(size_t)255;
        return p;
    };
    unsigned short* W0t = (unsigned short*)alloc((size_t)MF * 3 * 2048 * 2);   // 0.5 MB
    unsigned short* W1t = (unsigned short*)alloc((size_t)MF * 8 * 2048 * 2);   // 1.3 MB
    unsigned short* W2t = (unsigned short*)alloc((size_t)MF * 8 * 2048 * 2);   // 1.3 MB
    unsigned short* X1p = (unsigned short*)alloc((size_t)ROWS * LDIM * 2);     // 33.5 MB
    unsigned short* X2p = (unsigned short*)alloc((size_t)ROWS * LDIM * 2);     // 33.5 MB

    k_wprep<<<MF * 3 * 4, 64, 0, stream>>>(W0, W0t, 3, 40);
    k_wprep<<<MF * 8 * 4, 64, 0, stream>>>(W1, W1t, 8, 128);
    k_wprep<<<MF * 8 * 4, 64, 0, stream>>>(W2, W2t, 8, 128);

    k_gemm<3, true,  0,   true ><<<ROWS / 128, 256, 0, stream>>>(x, nullptr, W0t, X1p, out);
    k_gemm<8, false, 128, true ><<<ROWS / 128, 256, 0, stream>>>(x, X1p,     W1t, X2p, out);
    k_gemm<8, false, 256, false><<<ROWS / 128, 256, 0, stream>>>(x, X2p,     W2t, X2p, out);
}